// Round 12
// baseline (266.786 us; speedup 1.0000x reference)
//
#include <hip/hip_runtime.h>
#include <hip/hip_bf16.h>

#define NB 16
#define NP 1024
#define NS 32
#define NC 76
#define XSTR 104   // xb k-stride (shorts): 96 used + 8 pad
#define HSTR 136   // hb k-stride (shorts): 128 used + 8 pad
#define TPB 8      // 2-point tiles per block; 8192 tiles -> 1024 blocks = 4/CU

typedef __attribute__((ext_vector_type(8))) short bf16x8;
typedef __attribute__((ext_vector_type(4))) float f32x4;

__device__ inline short f2bf(float f) {
  unsigned u = __builtin_bit_cast(unsigned, f);
  u = u + 0x7fffu + ((u >> 16) & 1u);   // RNE
  return (short)(u >> 16);
}
__device__ inline unsigned cvt_pk_bf16(float lo, float hi) {
  unsigned r;
  asm("v_cvt_pk_bf16_f32 %0, %1, %2" : "=v"(r) : "v"(lo), "v"(hi));
  return r;
}
// Swizzle: fold col bits 4..5 (uniform per 16-col fragment window) into addr
// bits 3..4 (16B-granular; preserves b64/b128 alignment). Bijective.
__device__ inline int swzx(int col, int k) {
  return (col * XSTR + k) ^ (((col >> 4) & 3) << 3);
}
__device__ inline int swzh(int col, int k) {
  return (col * HSTR + k) ^ (((col >> 4) & 3) << 3);
}
// max across 16-lane groups via DPP butterfly (VALU pipe, no LDS)
__device__ inline float dpp_max16(float v) {
  int x;
  x = __builtin_amdgcn_update_dpp(0, __builtin_bit_cast(int, v), 0xB1, 0xf, 0xf, true);
  v = fmaxf(v, __builtin_bit_cast(float, x));
  x = __builtin_amdgcn_update_dpp(0, __builtin_bit_cast(int, v), 0x4E, 0xf, 0xf, true);
  v = fmaxf(v, __builtin_bit_cast(float, x));
  x = __builtin_amdgcn_update_dpp(0, __builtin_bit_cast(int, v), 0x141, 0xf, 0xf, true);
  v = fmaxf(v, __builtin_bit_cast(float, x));
  x = __builtin_amdgcn_update_dpp(0, __builtin_bit_cast(int, v), 0x140, 0xf, 0xf, true);
  v = fmaxf(v, __builtin_bit_cast(float, x));
  return v;
}
// sum within 16-lane groups via DPP
__device__ inline float dpp_add16(float v) {
  int x;
  x = __builtin_amdgcn_update_dpp(0, __builtin_bit_cast(int, v), 0xB1, 0xf, 0xf, true);
  v += __builtin_bit_cast(float, x);
  x = __builtin_amdgcn_update_dpp(0, __builtin_bit_cast(int, v), 0x4E, 0xf, 0xf, true);
  v += __builtin_bit_cast(float, x);
  x = __builtin_amdgcn_update_dpp(0, __builtin_bit_cast(int, v), 0x141, 0xf, 0xf, true);
  v += __builtin_bit_cast(float, x);
  x = __builtin_amdgcn_update_dpp(0, __builtin_bit_cast(int, v), 0x140, 0xf, 0xf, true);
  v += __builtin_bit_cast(float, x);
  return v;
}

// ---------------- single fused kernel: frames + MLP + pool ----------------
// 256 threads = 4 waves, each owning rows 32*wv..32*wv+31 (mf=0,1) over the
// FULL 64-col tile (nf=0..3). Tile = 2 points. Single xb/hb (30.7 KB).
// __launch_bounds__(256,4): 4 waves/EU -> 4 blocks/CU = 16 waves/CU in 4
// INDEPENDENT barrier groups. (R1-R11 data: the 2nd arg pins waves/EU; all
// (x,2) rounds were self-capped at 8 waves/CU. VGPR=112 <= 512/4=128 budget.)
// Loop (2 barriers/tile): L1(t)+h1store | bar | fill(t+1)+stage(t+2) overlap
// L2(t)+pool | bar. Frames fused in fill from STAGED sro registers.
// xb [col][k]: 0..63 feats(ch12..75); 64..66 R*rel; 67..69 R*o_n; 70..72
// dir_dif; 73 = 1.0 (bias row, static); 74..95 = 0 (static).
__global__ __launch_bounds__(256, 4)
void mlp_kernel(const float* __restrict__ inp, const float* __restrict__ w1g,
                const float* __restrict__ b1g, const float* __restrict__ w2g,
                const float* __restrict__ b2g, const float* __restrict__ normal,
                float* __restrict__ out) {
  __shared__ short xb[64 * XSTR];    // 13,312 B
  __shared__ short hb[64 * HSTR];    // 17,408 B
  const int tid = threadIdx.x;
  const int lane = tid & 63;
  const int wv = tid >> 6;          // wave 0..3 -> rows 32*wv..
  const int l15 = lane & 15;
  const int l4 = lane >> 4;         // 0..3

  const int tile0 = blockIdx.x * TPB;

  // fill-phase thread map (feats): 4 channels x 4 s per thread
  const int s4  = tid & 7;          // s quad
  const int flp = (tid >> 3) & 1;   // point within tile
  const int chq = tid >> 4;         // channel quad 0..15 -> k = 4*chq
  const int colb = flp*32 + 4*s4;

  // ----- weight fragments (rows 32*wv+16*mf+l15); b1 folded at kk=73 -----
  bf16x8 w1f[2][3];
#pragma unroll
  for (int mf = 0; mf < 2; ++mf)
#pragma unroll
    for (int ks = 0; ks < 3; ++ks) {
      bf16x8 a;
#pragma unroll
      for (int j = 0; j < 8; ++j) {
        int row = 32*wv + 16*mf + l15;
        int kk = 32*ks + 8*l4 + j;
        float v = 0.f;
        if (kk < 73) {
          int c = (kk < 64) ? (kk + 3) : ((kk < 67) ? (kk - 64) : kk);
          v = w1g[row*73 + c];
        } else if (kk == 73) {
          v = b1g[row];
        }
        a[j] = f2bf(v);
      }
      w1f[mf][ks] = a;
    }
  bf16x8 w2f[2][4];
#pragma unroll
  for (int mf = 0; mf < 2; ++mf)
#pragma unroll
    for (int ks = 0; ks < 4; ++ks) {
      // 8 consecutive floats, 32B-aligned -> two float4 loads
      const float* wp = w2g + (size_t)(32*wv + 16*mf + l15)*128 + 32*ks + 8*l4;
      float4 a0 = *(const float4*)wp;
      float4 a1 = *(const float4*)(wp + 4);
      bf16x8 a;
      a[0] = f2bf(a0.x); a[1] = f2bf(a0.y); a[2] = f2bf(a0.z); a[3] = f2bf(a0.w);
      a[4] = f2bf(a1.x); a[5] = f2bf(a1.y); a[6] = f2bf(a1.z); a[7] = f2bf(a1.w);
      w2f[mf][ks] = a;
    }
  float bias2[2][4];
#pragma unroll
  for (int mf = 0; mf < 2; ++mf)
#pragma unroll
    for (int r = 0; r < 4; ++r)
      bias2[mf][r] = b2g[32*wv + 16*mf + 4*l4 + r];

  // static pad region of xb: k=73 -> 1.0, (73,96) -> 0
  for (int i = tid; i < 64*23; i += 256) {
    int col = i / 23;
    int k = 73 + (i - col*23);
    xb[swzx(col, k)] = (k == 73) ? (short)0x3F80 : (short)0;
  }

  // ----- staging registers (next tile) -----
  float4 sf0, sf1, sf2, sf3;   // feats: 4 channels x 4 s
  float sro[9];                // rel/o_n/o_dir for (p,s)  (tid<64 only)
  auto stage = [&](int it2) {
    const int tile = tile0 + it2;
    const int bb = tile >> 9;
    const int pb = (tile & 511) * 2;
    const float* base = inp + ((size_t)((bb*NC + 12 + 4*chq)*NP) + pb + flp)*NS + 4*s4;
    sf0 = *(const float4*)(base + 0*(size_t)NP*NS);
    sf1 = *(const float4*)(base + 1*(size_t)NP*NS);
    sf2 = *(const float4*)(base + 2*(size_t)NP*NS);
    sf3 = *(const float4*)(base + 3*(size_t)NP*NS);
    if (tid < 64) {
      const int lp = tid >> 5, s = tid & 31;
      const int p = pb + lp;
#pragma unroll
      for (int i = 0; i < 3; ++i) {
        sro[i]   = inp[(size_t)((bb*NC + 6 + i)*NP + p)*NS + s];   // rel
        sro[3+i] = inp[(size_t)((bb*NC + 3 + i)*NP + p)*NS + s];   // o_n
        sro[6+i] = inp[(size_t)((bb*NC + 9 + i)*NP + p)*NS + s];   // o_dir
      }
    }
  };

  auto fill = [&](int it2) {
    const int tile = tile0 + it2;
    const int bb = tile >> 9;
    const int pb = (tile & 511) * 2;
    // frames inputs that are NOT staged: issue normal loads first (hidden
    // under the feat writes + reduce)
    float nr[3];
    if (tid < 64) {
      const int p = pb + (tid >> 5);
#pragma unroll
      for (int i = 0; i < 3; ++i) nr[i] = normal[(size_t)(bb*NP + p)*3 + i];
    }
    // feats from staged regs
    const float* f0 = (const float*)&sf0;
    const float* f1 = (const float*)&sf1;
    const float* f2 = (const float*)&sf2;
    const float* f3 = (const float*)&sf3;
#pragma unroll
    for (int j = 0; j < 4; ++j) {
      uint2 pk;
      pk.x = cvt_pk_bf16(f0[j], f1[j]);
      pk.y = cvt_pk_bf16(f2[j], f3[j]);
      *(uint2*)&xb[swzx(colb + j, 4*chq)] = pk;
    }
    // frames + aligned rows (tid<64: col = (lp,s)) from STAGED sro
    if (tid < 64) {
      const int col = tid;
      const int s = col & 31;
      const int p = pb + (col >> 5);
      // azi = mean over s=1..31: DPP sum16 + one xor16 shuffle
      float az[3];
#pragma unroll
      for (int i = 0; i < 3; ++i) {
        float sum = dpp_add16(sro[i]);
        sum += __shfl_xor(sum, 16);
        float v0 = __shfl(sro[i], lane & 32);    // s==0 lane of this group
        az[i] = (sum - v0) * (1.f/31.f);
      }
      float nn = sqrtf(nr[0]*nr[0] + nr[1]*nr[1] + nr[2]*nr[2]) + 1e-8f;
      nr[0] /= nn; nr[1] /= nn; nr[2] /= nn;
      float an = sqrtf(az[0]*az[0] + az[1]*az[1] + az[2]*az[2]) + 1e-8f;
      float au[3] = {az[0]/an, az[1]/an, az[2]/an};
      float d = au[0]*nr[0] + au[1]*nr[1] + au[2]*nr[2];
      float xax[3] = {au[0] - d*nr[0], au[1] - d*nr[1], au[2] - d*nr[2]};
      float xn = sqrtf(xax[0]*xax[0] + xax[1]*xax[1] + xax[2]*xax[2]) + 1e-8f;
      xax[0] /= xn; xax[1] /= xn; xax[2] /= xn;
      float yax[3] = {nr[1]*xax[2] - nr[2]*xax[1],
                      nr[2]*xax[0] - nr[0]*xax[2],
                      nr[0]*xax[1] - nr[1]*xax[0]};
      if (s < 3) {    // azi_u -> out channels 0..2
        float o = (s == 0) ? au[0] : ((s == 1) ? au[1] : au[2]);
        out[(size_t)(bb*131 + s)*NP + p] = o;
      }
      float xv[9];
#pragma unroll
      for (int r = 0; r < 3; ++r) {
        const float* Rr = (r == 0) ? xax : ((r == 1) ? yax : nr);
        xv[r]   = Rr[0]*sro[0] + Rr[1]*sro[1] + Rr[2]*sro[2];
        xv[3+r] = Rr[0]*sro[3] + Rr[1]*sro[4] + Rr[2]*sro[5];
        xv[6+r] = (Rr[0]*au[0] + Rr[1]*au[1] + Rr[2]*au[2])
                - (Rr[0]*sro[6] + Rr[1]*sro[7] + Rr[2]*sro[8]);
      }
      int4 pk;
      pk.x = (int)cvt_pk_bf16(xv[0], xv[1]);
      pk.y = (int)cvt_pk_bf16(xv[2], xv[3]);
      pk.z = (int)cvt_pk_bf16(xv[4], xv[5]);
      pk.w = (int)cvt_pk_bf16(xv[6], xv[7]);
      *(int4*)&xb[swzx(col, 64)] = pk;
      xb[swzx(col, 72)] = f2bf(xv[8]);
    }
  };

  // ----- prologue -----
  stage(0);
  fill(0);
  stage(1);
  __syncthreads();                       // xb(0) visible

  for (int it = 0; it < TPB; ++it) {
    const int tile = tile0 + it;
    const int bb = tile >> 9;
    const int pb = (tile & 511) * 2;

    // ----- layer 1: h1 = relu(w1 @ x) (bias via ones-row), K=96 -----
    f32x4 acc1[2][4];
#pragma unroll
    for (int mf = 0; mf < 2; ++mf)
#pragma unroll
      for (int nf = 0; nf < 4; ++nf) acc1[mf][nf] = f32x4{0.f,0.f,0.f,0.f};
#pragma unroll
    for (int ks = 0; ks < 3; ++ks) {
      bf16x8 bv[4];
#pragma unroll
      for (int nf = 0; nf < 4; ++nf)
        bv[nf] = *(const bf16x8*)&xb[swzx(16*nf + l15, 32*ks + 8*l4)];
#pragma unroll
      for (int mf = 0; mf < 2; ++mf)
#pragma unroll
        for (int nf = 0; nf < 4; ++nf)
          acc1[mf][nf] = __builtin_amdgcn_mfma_f32_16x16x32_bf16(
              w1f[mf][ks], bv[nf], acc1[mf][nf], 0, 0, 0);
    }
    // h1 -> hb (relu, cvt_pk, b64)
#pragma unroll
    for (int mf = 0; mf < 2; ++mf)
#pragma unroll
      for (int nf = 0; nf < 4; ++nf) {
        const int col = 16*nf + l15;
        const int row0 = 32*wv + 16*mf + 4*l4;
        uint2 pk;
        pk.x = cvt_pk_bf16(fmaxf(acc1[mf][nf][0], 0.f), fmaxf(acc1[mf][nf][1], 0.f));
        pk.y = cvt_pk_bf16(fmaxf(acc1[mf][nf][2], 0.f), fmaxf(acc1[mf][nf][3], 0.f));
        *(uint2*)&hb[swzh(col, row0)] = pk;
      }
    __syncthreads();                     // xb reads done; hb visible

    // x(it+1) fill + stage(it+2) overlap layer-2 compute
    if (it + 1 < TPB) fill(it + 1);
    if (it + 2 < TPB) stage(it + 2);

    // ----- layer 2: h2 = relu(w2 @ h1 + b2), K=128 -----
    f32x4 acc2[2][4];
#pragma unroll
    for (int mf = 0; mf < 2; ++mf)
#pragma unroll
      for (int nf = 0; nf < 4; ++nf) acc2[mf][nf] = f32x4{0.f,0.f,0.f,0.f};
#pragma unroll
    for (int ks = 0; ks < 4; ++ks) {
      bf16x8 bv[4];
#pragma unroll
      for (int nf = 0; nf < 4; ++nf)
        bv[nf] = *(const bf16x8*)&hb[swzh(16*nf + l15, 32*ks + 8*l4)];
#pragma unroll
      for (int mf = 0; mf < 2; ++mf)
#pragma unroll
        for (int nf = 0; nf < 4; ++nf)
          acc2[mf][nf] = __builtin_amdgcn_mfma_f32_16x16x32_bf16(
              w2f[mf][ks], bv[nf], acc2[mf][nf], 0, 0, 0);
    }

    // ----- relu + max-pool over s (DPP butterfly) + store -----
    // point0 = cols 0..31 (nf 0,1), point1 = cols 32..63 (nf 2,3)
#pragma unroll
    for (int mf = 0; mf < 2; ++mf)
#pragma unroll
      for (int r = 0; r < 4; ++r) {
        float v0 = fmaxf(acc2[mf][0][r], acc2[mf][1][r]);
        float v1 = fmaxf(acc2[mf][2][r], acc2[mf][3][r]);
        v0 = dpp_max16(v0);
        v1 = dpp_max16(v1);
        v0 = fmaxf(v0 + bias2[mf][r], 0.f);
        v1 = fmaxf(v1 + bias2[mf][r], 0.f);
        if (l15 == 0) {
          const int row = 32*wv + 16*mf + 4*l4 + r;
          *(float2*)&out[(size_t)(bb*131 + 3 + row)*NP + pb] = float2{v0, v1};
        }
      }
    __syncthreads();                     // hb reads done; xb(it+1) visible
  }
}

extern "C" void kernel_launch(void* const* d_in, const int* in_sizes, int n_in,
                              void* d_out, int out_size, void* d_ws, size_t ws_size,
                              hipStream_t stream) {
  const float* inp    = (const float*)d_in[0];
  const float* normal = (const float*)d_in[1];
  const float* w1     = (const float*)d_in[2];
  const float* b1     = (const float*)d_in[3];
  const float* w2     = (const float*)d_in[4];
  const float* b2     = (const float*)d_in[5];
  float* out = (float*)d_out;

  // 8192 two-point tiles / TPB=8 -> 1024 blocks; 30.7 KB LDS, VGPR<=128
  // -> 4 blocks/CU = 16 waves/CU
  mlp_kernel<<<dim3(NB*NP/2/TPB), dim3(256), 0, stream>>>(
      inp, w1, b1, w2, b2, normal, out);
}

// Round 13
// 71.745 us; speedup vs baseline: 3.7185x; 3.7185x over previous
//
#include <hip/hip_runtime.h>
#include <hip/hip_bf16.h>

#define NB 16
#define NP 1024
#define NS 32
#define NC 76
#define XSTR 104   // xb k-stride (shorts): 96 used + 8 pad
#define HSTR 136   // hb k-stride (shorts): 128 used + 8 pad
#define TPB 8      // 2-point tiles per block; 8192 tiles -> 1024 blocks

typedef __attribute__((ext_vector_type(8))) short bf16x8;
typedef __attribute__((ext_vector_type(4))) float f32x4;

__device__ inline short f2bf(float f) {
  unsigned u = __builtin_bit_cast(unsigned, f);
  u = u + 0x7fffu + ((u >> 16) & 1u);   // RNE
  return (short)(u >> 16);
}
__device__ inline unsigned cvt_pk_bf16(float lo, float hi) {
  unsigned r;
  asm("v_cvt_pk_bf16_f32 %0, %1, %2" : "=v"(r) : "v"(lo), "v"(hi));
  return r;
}
// Swizzle: fold col bits 4..5 (uniform per 16-col fragment window) into addr
// bits 3..4 (16B-granular; preserves b64/b128 alignment). Bijective.
__device__ inline int swzx(int col, int k) {
  return (col * XSTR + k) ^ (((col >> 4) & 3) << 3);
}
__device__ inline int swzh(int col, int k) {
  return (col * HSTR + k) ^ (((col >> 4) & 3) << 3);
}
// max across 16-lane groups via DPP butterfly (VALU pipe, no LDS)
__device__ inline float dpp_max16(float v) {
  int x;
  x = __builtin_amdgcn_update_dpp(0, __builtin_bit_cast(int, v), 0xB1, 0xf, 0xf, true);
  v = fmaxf(v, __builtin_bit_cast(float, x));
  x = __builtin_amdgcn_update_dpp(0, __builtin_bit_cast(int, v), 0x4E, 0xf, 0xf, true);
  v = fmaxf(v, __builtin_bit_cast(float, x));
  x = __builtin_amdgcn_update_dpp(0, __builtin_bit_cast(int, v), 0x141, 0xf, 0xf, true);
  v = fmaxf(v, __builtin_bit_cast(float, x));
  x = __builtin_amdgcn_update_dpp(0, __builtin_bit_cast(int, v), 0x140, 0xf, 0xf, true);
  v = fmaxf(v, __builtin_bit_cast(float, x));
  return v;
}
// sum within 16-lane groups via DPP
__device__ inline float dpp_add16(float v) {
  int x;
  x = __builtin_amdgcn_update_dpp(0, __builtin_bit_cast(int, v), 0xB1, 0xf, 0xf, true);
  v += __builtin_bit_cast(float, x);
  x = __builtin_amdgcn_update_dpp(0, __builtin_bit_cast(int, v), 0x4E, 0xf, 0xf, true);
  v += __builtin_bit_cast(float, x);
  x = __builtin_amdgcn_update_dpp(0, __builtin_bit_cast(int, v), 0x141, 0xf, 0xf, true);
  v += __builtin_bit_cast(float, x);
  x = __builtin_amdgcn_update_dpp(0, __builtin_bit_cast(int, v), 0x140, 0xf, 0xf, true);
  v += __builtin_bit_cast(float, x);
  return v;
}

// ---------------- single fused kernel: frames + MLP + pool ----------------
// 256 threads = 4 waves, each owning rows 32*wv..32*wv+31 (mf=0,1) over the
// FULL 64-col tile (nf=0..3). Tile = 2 points. Single xb/hb (30.7 KB).
// REGISTER MODEL (unified VGPR+AGPR file, r12 lesson): occupancy = 512 /
// (arch + acc). R11 = 112 arch + 64 acc (acc1,acc2 separate) = 176 -> 2
// waves/SIMD. THIS kernel shares ONE acc[2][4] across both layers ->
// ~112 + 32 = ~144 -> 3 waves/SIMD = 12 waves/CU, 3 independent barrier
// groups. NO launch-bounds cap (R2/R9/R12: any cap below natural usage
// collapses the allocator to 64 + full spill).
// Loop (2 barriers/tile): L1(t)+h1store | bar | fill(t+1)+stage(t+2) overlap
// L2(t)+pool | bar. Frames fused in fill from STAGED sro registers.
// xb [col][k]: 0..63 feats(ch12..75); 64..66 R*rel; 67..69 R*o_n; 70..72
// dir_dif; 73 = 1.0 (bias row, static); 74..95 = 0 (static).
__global__ __launch_bounds__(256, 2)
void mlp_kernel(const float* __restrict__ inp, const float* __restrict__ w1g,
                const float* __restrict__ b1g, const float* __restrict__ w2g,
                const float* __restrict__ b2g, const float* __restrict__ normal,
                float* __restrict__ out) {
  __shared__ short xb[64 * XSTR];    // 13,312 B
  __shared__ short hb[64 * HSTR];    // 17,408 B
  const int tid = threadIdx.x;
  const int lane = tid & 63;
  const int wv = tid >> 6;          // wave 0..3 -> rows 32*wv..
  const int l15 = lane & 15;
  const int l4 = lane >> 4;         // 0..3

  const int tile0 = blockIdx.x * TPB;

  // fill-phase thread map (feats): 4 channels x 4 s per thread
  const int s4  = tid & 7;          // s quad
  const int flp = (tid >> 3) & 1;   // point within tile
  const int chq = tid >> 4;         // channel quad 0..15 -> k = 4*chq
  const int colb = flp*32 + 4*s4;

  // ----- weight fragments (rows 32*wv+16*mf+l15); b1 folded at kk=73 -----
  bf16x8 w1f[2][3];
#pragma unroll
  for (int mf = 0; mf < 2; ++mf)
#pragma unroll
    for (int ks = 0; ks < 3; ++ks) {
      bf16x8 a;
#pragma unroll
      for (int j = 0; j < 8; ++j) {
        int row = 32*wv + 16*mf + l15;
        int kk = 32*ks + 8*l4 + j;
        float v = 0.f;
        if (kk < 73) {
          int c = (kk < 64) ? (kk + 3) : ((kk < 67) ? (kk - 64) : kk);
          v = w1g[row*73 + c];
        } else if (kk == 73) {
          v = b1g[row];
        }
        a[j] = f2bf(v);
      }
      w1f[mf][ks] = a;
    }
  bf16x8 w2f[2][4];
#pragma unroll
  for (int mf = 0; mf < 2; ++mf)
#pragma unroll
    for (int ks = 0; ks < 4; ++ks) {
      // 8 consecutive floats, 32B-aligned -> two float4 loads
      const float* wp = w2g + (size_t)(32*wv + 16*mf + l15)*128 + 32*ks + 8*l4;
      float4 a0 = *(const float4*)wp;
      float4 a1 = *(const float4*)(wp + 4);
      bf16x8 a;
      a[0] = f2bf(a0.x); a[1] = f2bf(a0.y); a[2] = f2bf(a0.z); a[3] = f2bf(a0.w);
      a[4] = f2bf(a1.x); a[5] = f2bf(a1.y); a[6] = f2bf(a1.z); a[7] = f2bf(a1.w);
      w2f[mf][ks] = a;
    }
  float bias2[2][4];
#pragma unroll
  for (int mf = 0; mf < 2; ++mf)
#pragma unroll
    for (int r = 0; r < 4; ++r)
      bias2[mf][r] = b2g[32*wv + 16*mf + 4*l4 + r];

  // static pad region of xb: k=73 -> 1.0, (73,96) -> 0
  for (int i = tid; i < 64*23; i += 256) {
    int col = i / 23;
    int k = 73 + (i - col*23);
    xb[swzx(col, k)] = (k == 73) ? (short)0x3F80 : (short)0;
  }

  // ----- staging registers (next tile) -----
  float4 sf0, sf1, sf2, sf3;   // feats: 4 channels x 4 s
  float sro[9];                // rel/o_n/o_dir for (p,s)  (tid<64 only)
  auto stage = [&](int it2) {
    const int tile = tile0 + it2;
    const int bb = tile >> 9;
    const int pb = (tile & 511) * 2;
    const float* base = inp + ((size_t)((bb*NC + 12 + 4*chq)*NP) + pb + flp)*NS + 4*s4;
    sf0 = *(const float4*)(base + 0*(size_t)NP*NS);
    sf1 = *(const float4*)(base + 1*(size_t)NP*NS);
    sf2 = *(const float4*)(base + 2*(size_t)NP*NS);
    sf3 = *(const float4*)(base + 3*(size_t)NP*NS);
    if (tid < 64) {
      const int lp = tid >> 5, s = tid & 31;
      const int p = pb + lp;
#pragma unroll
      for (int i = 0; i < 3; ++i) {
        sro[i]   = inp[(size_t)((bb*NC + 6 + i)*NP + p)*NS + s];   // rel
        sro[3+i] = inp[(size_t)((bb*NC + 3 + i)*NP + p)*NS + s];   // o_n
        sro[6+i] = inp[(size_t)((bb*NC + 9 + i)*NP + p)*NS + s];   // o_dir
      }
    }
  };

  auto fill = [&](int it2) {
    const int tile = tile0 + it2;
    const int bb = tile >> 9;
    const int pb = (tile & 511) * 2;
    // frames input not staged: issue normal loads first (hidden under writes)
    float nr[3];
    if (tid < 64) {
      const int p = pb + (tid >> 5);
#pragma unroll
      for (int i = 0; i < 3; ++i) nr[i] = normal[(size_t)(bb*NP + p)*3 + i];
    }
    // feats from staged regs
    const float* f0 = (const float*)&sf0;
    const float* f1 = (const float*)&sf1;
    const float* f2 = (const float*)&sf2;
    const float* f3 = (const float*)&sf3;
#pragma unroll
    for (int j = 0; j < 4; ++j) {
      uint2 pk;
      pk.x = cvt_pk_bf16(f0[j], f1[j]);
      pk.y = cvt_pk_bf16(f2[j], f3[j]);
      *(uint2*)&xb[swzx(colb + j, 4*chq)] = pk;
    }
    // frames + aligned rows (tid<64: col = (lp,s)) from STAGED sro
    if (tid < 64) {
      const int col = tid;
      const int s = col & 31;
      const int p = pb + (col >> 5);
      // azi = mean over s=1..31: DPP sum16 + one xor16 shuffle
      float az[3];
#pragma unroll
      for (int i = 0; i < 3; ++i) {
        float sum = dpp_add16(sro[i]);
        sum += __shfl_xor(sum, 16);
        float v0 = __shfl(sro[i], lane & 32);    // s==0 lane of this group
        az[i] = (sum - v0) * (1.f/31.f);
      }
      float nn = sqrtf(nr[0]*nr[0] + nr[1]*nr[1] + nr[2]*nr[2]) + 1e-8f;
      nr[0] /= nn; nr[1] /= nn; nr[2] /= nn;
      float an = sqrtf(az[0]*az[0] + az[1]*az[1] + az[2]*az[2]) + 1e-8f;
      float au[3] = {az[0]/an, az[1]/an, az[2]/an};
      float d = au[0]*nr[0] + au[1]*nr[1] + au[2]*nr[2];
      float xax[3] = {au[0] - d*nr[0], au[1] - d*nr[1], au[2] - d*nr[2]};
      float xn = sqrtf(xax[0]*xax[0] + xax[1]*xax[1] + xax[2]*xax[2]) + 1e-8f;
      xax[0] /= xn; xax[1] /= xn; xax[2] /= xn;
      float yax[3] = {nr[1]*xax[2] - nr[2]*xax[1],
                      nr[2]*xax[0] - nr[0]*xax[2],
                      nr[0]*xax[1] - nr[1]*xax[0]};
      if (s < 3) {    // azi_u -> out channels 0..2
        float o = (s == 0) ? au[0] : ((s == 1) ? au[1] : au[2]);
        out[(size_t)(bb*131 + s)*NP + p] = o;
      }
      float xv[9];
#pragma unroll
      for (int r = 0; r < 3; ++r) {
        const float* Rr = (r == 0) ? xax : ((r == 1) ? yax : nr);
        xv[r]   = Rr[0]*sro[0] + Rr[1]*sro[1] + Rr[2]*sro[2];
        xv[3+r] = Rr[0]*sro[3] + Rr[1]*sro[4] + Rr[2]*sro[5];
        xv[6+r] = (Rr[0]*au[0] + Rr[1]*au[1] + Rr[2]*au[2])
                - (Rr[0]*sro[6] + Rr[1]*sro[7] + Rr[2]*sro[8]);
      }
      int4 pk;
      pk.x = (int)cvt_pk_bf16(xv[0], xv[1]);
      pk.y = (int)cvt_pk_bf16(xv[2], xv[3]);
      pk.z = (int)cvt_pk_bf16(xv[4], xv[5]);
      pk.w = (int)cvt_pk_bf16(xv[6], xv[7]);
      *(int4*)&xb[swzx(col, 64)] = pk;
      xb[swzx(col, 72)] = f2bf(xv[8]);
    }
  };

  // ----- prologue -----
  stage(0);
  fill(0);
  stage(1);
  __syncthreads();                       // xb(0) visible

  // ONE accumulator array, reused by both layers (halves AGPR footprint:
  // 64 -> 32; liveness is disjoint — L1's acc dies into the h1 store).
  f32x4 acc[2][4];

  for (int it = 0; it < TPB; ++it) {
    const int tile = tile0 + it;
    const int bb = tile >> 9;
    const int pb = (tile & 511) * 2;

    // ----- layer 1: h1 = relu(w1 @ x) (bias via ones-row), K=96 -----
#pragma unroll
    for (int mf = 0; mf < 2; ++mf)
#pragma unroll
      for (int nf = 0; nf < 4; ++nf) acc[mf][nf] = f32x4{0.f,0.f,0.f,0.f};
#pragma unroll
    for (int ks = 0; ks < 3; ++ks) {
      bf16x8 bv[4];
#pragma unroll
      for (int nf = 0; nf < 4; ++nf)
        bv[nf] = *(const bf16x8*)&xb[swzx(16*nf + l15, 32*ks + 8*l4)];
#pragma unroll
      for (int mf = 0; mf < 2; ++mf)
#pragma unroll
        for (int nf = 0; nf < 4; ++nf)
          acc[mf][nf] = __builtin_amdgcn_mfma_f32_16x16x32_bf16(
              w1f[mf][ks], bv[nf], acc[mf][nf], 0, 0, 0);
    }
    // h1 -> hb (relu, cvt_pk, b64); acc dies here
#pragma unroll
    for (int mf = 0; mf < 2; ++mf)
#pragma unroll
      for (int nf = 0; nf < 4; ++nf) {
        const int col = 16*nf + l15;
        const int row0 = 32*wv + 16*mf + 4*l4;
        uint2 pk;
        pk.x = cvt_pk_bf16(fmaxf(acc[mf][nf][0], 0.f), fmaxf(acc[mf][nf][1], 0.f));
        pk.y = cvt_pk_bf16(fmaxf(acc[mf][nf][2], 0.f), fmaxf(acc[mf][nf][3], 0.f));
        *(uint2*)&hb[swzh(col, row0)] = pk;
      }
    __syncthreads();                     // xb reads done; hb visible

    // x(it+1) fill + stage(it+2) overlap layer-2 compute
    if (it + 1 < TPB) fill(it + 1);
    if (it + 2 < TPB) stage(it + 2);

    // ----- layer 2: h2 = relu(w2 @ h1 + b2), K=128 (same acc regs) -----
#pragma unroll
    for (int mf = 0; mf < 2; ++mf)
#pragma unroll
      for (int nf = 0; nf < 4; ++nf) acc[mf][nf] = f32x4{0.f,0.f,0.f,0.f};
#pragma unroll
    for (int ks = 0; ks < 4; ++ks) {
      bf16x8 bv[4];
#pragma unroll
      for (int nf = 0; nf < 4; ++nf)
        bv[nf] = *(const bf16x8*)&hb[swzh(16*nf + l15, 32*ks + 8*l4)];
#pragma unroll
      for (int mf = 0; mf < 2; ++mf)
#pragma unroll
        for (int nf = 0; nf < 4; ++nf)
          acc[mf][nf] = __builtin_amdgcn_mfma_f32_16x16x32_bf16(
              w2f[mf][ks], bv[nf], acc[mf][nf], 0, 0, 0);
    }

    // ----- relu + max-pool over s (DPP butterfly) + store -----
    // point0 = cols 0..31 (nf 0,1), point1 = cols 32..63 (nf 2,3)
#pragma unroll
    for (int mf = 0; mf < 2; ++mf)
#pragma unroll
      for (int r = 0; r < 4; ++r) {
        float v0 = fmaxf(acc[mf][0][r], acc[mf][1][r]);
        float v1 = fmaxf(acc[mf][2][r], acc[mf][3][r]);
        v0 = dpp_max16(v0);
        v1 = dpp_max16(v1);
        v0 = fmaxf(v0 + bias2[mf][r], 0.f);
        v1 = fmaxf(v1 + bias2[mf][r], 0.f);
        if (l15 == 0) {
          const int row = 32*wv + 16*mf + 4*l4 + r;
          *(float2*)&out[(size_t)(bb*131 + 3 + row)*NP + pb] = float2{v0, v1};
        }
      }
    __syncthreads();                     // hb reads done; xb(it+1) visible
  }
}

extern "C" void kernel_launch(void* const* d_in, const int* in_sizes, int n_in,
                              void* d_out, int out_size, void* d_ws, size_t ws_size,
                              hipStream_t stream) {
  const float* inp    = (const float*)d_in[0];
  const float* normal = (const float*)d_in[1];
  const float* w1     = (const float*)d_in[2];
  const float* b1     = (const float*)d_in[3];
  const float* w2     = (const float*)d_in[4];
  const float* b2     = (const float*)d_in[5];
  float* out = (float*)d_out;

  // 8192 two-point tiles / TPB=8 -> 1024 blocks; 30.7 KB LDS
  mlp_kernel<<<dim3(NB*NP/2/TPB), dim3(256), 0, stream>>>(
      inp, w1, b1, w2, b2, normal, out);
}

// Round 14
// 61.038 us; speedup vs baseline: 4.3708x; 1.1754x over previous
//
#include <hip/hip_runtime.h>
#include <hip/hip_bf16.h>

#define NB 16
#define NP 1024
#define NS 32
#define NC 76
#define XSTR 104   // xb k-stride (shorts): 96 used + 8 pad
#define HSTR 136   // hb k-stride (shorts): 128 used + 8 pad
#define TPB 16     // 4-point tiles per block; 4096 tiles -> 256 blocks = 1/CU

typedef __attribute__((ext_vector_type(8))) short bf16x8;
typedef __attribute__((ext_vector_type(4))) float f32x4;

__device__ inline short f2bf(float f) {
  unsigned u = __builtin_bit_cast(unsigned, f);
  u = u + 0x7fffu + ((u >> 16) & 1u);   // RNE
  return (short)(u >> 16);
}
__device__ inline unsigned cvt_pk_bf16(float lo, float hi) {
  unsigned r;
  asm("v_cvt_pk_bf16_f32 %0, %1, %2" : "=v"(r) : "v"(lo), "v"(hi));
  return r;
}
// Swizzle: fold col bits 4..6 (uniform per 16-col fragment window -> read
// bank-pattern untouched) into addr bits 3..5 (16B-granular). Bijective.
__device__ inline int swzx(int col, int k) {
  return (col * XSTR + k) ^ (((col >> 4) & 7) << 3);
}
__device__ inline int swzh(int col, int k) {
  return (col * HSTR + k) ^ (((col >> 4) & 7) << 3);
}
// sum within 16-lane groups via DPP (frames azi reduce)
__device__ inline float dpp_add16(float v) {
  int x;
  x = __builtin_amdgcn_update_dpp(0, __builtin_bit_cast(int, v), 0xB1, 0xf, 0xf, true);
  v += __builtin_bit_cast(float, x);
  x = __builtin_amdgcn_update_dpp(0, __builtin_bit_cast(int, v), 0x4E, 0xf, 0xf, true);
  v += __builtin_bit_cast(float, x);
  x = __builtin_amdgcn_update_dpp(0, __builtin_bit_cast(int, v), 0x141, 0xf, 0xf, true);
  v += __builtin_bit_cast(float, x);
  x = __builtin_amdgcn_update_dpp(0, __builtin_bit_cast(int, v), 0x140, 0xf, 0xf, true);
  v += __builtin_bit_cast(float, x);
  return v;
}

// ---------------- single fused kernel: frames + MLP + pool ----------------
// R8 skeleton (proven 60.8 us): 512 threads = 8 waves; wave wv owns output
// rows 16*wv..16*wv+15 over the full 128-col tile (4 points). xb/hb double-
// buffered (122.9 KB, 1 block/CU), ONE barrier per tile:
//   L2(t)+pool | L1(t+1)+h1store | fill(t+2) | stage(t+3) | bar.
// NEW (R14): layer-2 uses SWAPPED MFMA operands — mfma(A=h1-frag, B=w2-frag)
// so D[row = s-sub = 4*l4+reg][col = out-row = l15]. The s-pool then reduces
// over reg (3 fmax) + nf-pair (1 fmax) + l4 groups (shfl_xor 16/32), and the
// store is one unmasked 64-lane op (row=l15, point=l4). ~56 VALU ops vs ~290
// for the old per-output DPP butterfly.
// xb [col][k]: 0..63 feats(ch12..75); 64..66 R*rel; 67..69 R*o_n; 70..72
// dir_dif; 73 = 1.0 (bias-1 row, static); 74..95 = 0 (static).
__global__ __launch_bounds__(512, 2)
void mlp_kernel(const float* __restrict__ inp, const float* __restrict__ w1g,
                const float* __restrict__ b1g, const float* __restrict__ w2g,
                const float* __restrict__ b2g, const float* __restrict__ normal,
                float* __restrict__ out) {
  __shared__ short xb[2][128 * XSTR];   // 2 x 26,624 B
  __shared__ short hb[2][128 * HSTR];   // 2 x 34,816 B
  const int tid = threadIdx.x;
  const int lane = tid & 63;
  const int wv = tid >> 6;          // wave 0..7 -> rows 16*wv..
  const int l15 = lane & 15;
  const int l4 = lane >> 4;         // 0..3

  const int tile0 = blockIdx.x * TPB;

  // fill-phase thread map (feats)
  const int s4  = tid & 7;          // s quad
  const int flp = (tid >> 3) & 3;   // point within tile
  const int chq = tid >> 5;         // channel quad 0..15 -> k = 4*chq
  const int colb = flp*32 + 4*s4;

  // ----- weight fragments (rows 16*wv+l15); b1 folded at kk=73 -----
  bf16x8 w1f[3];
#pragma unroll
  for (int ks = 0; ks < 3; ++ks) {
    bf16x8 a;
#pragma unroll
    for (int j = 0; j < 8; ++j) {
      int row = 16*wv + l15;
      int kk = 32*ks + 8*l4 + j;
      float v = 0.f;
      if (kk < 73) {
        int c = (kk < 64) ? (kk + 3) : ((kk < 67) ? (kk - 64) : kk);
        v = w1g[row*73 + c];
      } else if (kk == 73) {
        v = b1g[row];
      }
      a[j] = f2bf(v);
    }
    w1f[ks] = a;
  }
  bf16x8 w2f[4];
#pragma unroll
  for (int ks = 0; ks < 4; ++ks) {
    const float* wp = w2g + (size_t)(16*wv + l15)*128 + 32*ks + 8*l4;
    float4 a0 = *(const float4*)wp;
    float4 a1 = *(const float4*)(wp + 4);
    bf16x8 a;
    a[0] = f2bf(a0.x); a[1] = f2bf(a0.y); a[2] = f2bf(a0.z); a[3] = f2bf(a0.w);
    a[4] = f2bf(a1.x); a[5] = f2bf(a1.y); a[6] = f2bf(a1.z); a[7] = f2bf(a1.w);
    w2f[ks] = a;
  }
  const float bias2s = b2g[16*wv + l15];   // out-row = l15 under swapped L2

  // static pad region of BOTH xb buffers: k=73 -> 1.0, (73,96) -> 0
  for (int i = tid; i < 2*128*23; i += 512) {
    int bufi = i / (128*23);
    int r = i - bufi*(128*23);
    int col = r / 23;
    int k = 73 + (r - col*23);
    xb[bufi][swzx(col, k)] = (k == 73) ? (short)0x3F80 : (short)0;
  }

  // ----- staging registers -----
  float4 sf0, sf1, sf2, sf3;    // feats: 4 channels x 4 s
  float sro[9];                 // rel/o_n/o_dir for (p, s) (tid<128)
  auto stage = [&](int it2) {
    const int tile = tile0 + it2;
    const int bb = tile >> 8;
    const int pb = (tile & 255) * 4;
    const float* base = inp + ((size_t)((bb*NC + 12 + 4*chq)*NP) + pb + flp)*NS + 4*s4;
    sf0 = *(const float4*)(base + 0*(size_t)NP*NS);
    sf1 = *(const float4*)(base + 1*(size_t)NP*NS);
    sf2 = *(const float4*)(base + 2*(size_t)NP*NS);
    sf3 = *(const float4*)(base + 3*(size_t)NP*NS);
    if (tid < 128) {
      const int lp = tid >> 5, s = tid & 31;
      const int p = pb + lp;
#pragma unroll
      for (int i = 0; i < 3; ++i) {
        sro[i]   = inp[(size_t)((bb*NC + 6 + i)*NP + p)*NS + s];   // rel
        sro[3+i] = inp[(size_t)((bb*NC + 3 + i)*NP + p)*NS + s];   // o_n
        sro[6+i] = inp[(size_t)((bb*NC + 9 + i)*NP + p)*NS + s];   // o_dir
      }
    }
  };

  auto fill = [&](int it2, int bufi) {
    const int tile = tile0 + it2;
    const int bb = tile >> 8;
    const int pb = (tile & 255) * 4;
    float nr[3];
    if (tid < 128) {   // issue normal loads early (hide under feat writes)
      const int p = pb + (tid >> 5);
#pragma unroll
      for (int i = 0; i < 3; ++i) nr[i] = normal[(size_t)(bb*NP + p)*3 + i];
    }
    const float* f0 = (const float*)&sf0;
    const float* f1 = (const float*)&sf1;
    const float* f2 = (const float*)&sf2;
    const float* f3 = (const float*)&sf3;
#pragma unroll
    for (int j = 0; j < 4; ++j) {
      uint2 pk;
      pk.x = cvt_pk_bf16(f0[j], f1[j]);
      pk.y = cvt_pk_bf16(f2[j], f3[j]);
      *(uint2*)&xb[bufi][swzx(colb + j, 4*chq)] = pk;
    }
    if (tid < 128) {
      const int col = tid;
      const int s = col & 31;
      const int p = pb + (col >> 5);
      // azi = mean over s=1..31 (16-lane DPP sum + xor16 within the s-group)
      float az[3];
#pragma unroll
      for (int i = 0; i < 3; ++i) {
        float sum = dpp_add16(sro[i]);
        sum += __shfl_xor(sum, 16);
        float v0 = __shfl(sro[i], lane & 32);    // s==0 lane of this group
        az[i] = (sum - v0) * (1.f/31.f);
      }
      float nn = sqrtf(nr[0]*nr[0] + nr[1]*nr[1] + nr[2]*nr[2]) + 1e-8f;
      nr[0] /= nn; nr[1] /= nn; nr[2] /= nn;
      float an = sqrtf(az[0]*az[0] + az[1]*az[1] + az[2]*az[2]) + 1e-8f;
      float au[3] = {az[0]/an, az[1]/an, az[2]/an};
      float d = au[0]*nr[0] + au[1]*nr[1] + au[2]*nr[2];
      float xax[3] = {au[0] - d*nr[0], au[1] - d*nr[1], au[2] - d*nr[2]};
      float xn = sqrtf(xax[0]*xax[0] + xax[1]*xax[1] + xax[2]*xax[2]) + 1e-8f;
      xax[0] /= xn; xax[1] /= xn; xax[2] /= xn;
      float yax[3] = {nr[1]*xax[2] - nr[2]*xax[1],
                      nr[2]*xax[0] - nr[0]*xax[2],
                      nr[0]*xax[1] - nr[1]*xax[0]};
      if (s < 3) {    // azi_u -> out channels 0..2
        float o = (s == 0) ? au[0] : ((s == 1) ? au[1] : au[2]);
        out[(size_t)(bb*131 + s)*NP + p] = o;
      }
      float xv[9];
#pragma unroll
      for (int r = 0; r < 3; ++r) {
        const float* Rr = (r == 0) ? xax : ((r == 1) ? yax : nr);
        xv[r]   = Rr[0]*sro[0] + Rr[1]*sro[1] + Rr[2]*sro[2];
        xv[3+r] = Rr[0]*sro[3] + Rr[1]*sro[4] + Rr[2]*sro[5];
        xv[6+r] = (Rr[0]*au[0] + Rr[1]*au[1] + Rr[2]*au[2])
                - (Rr[0]*sro[6] + Rr[1]*sro[7] + Rr[2]*sro[8]);
      }
      int4 pk;
      pk.x = (int)cvt_pk_bf16(xv[0], xv[1]);
      pk.y = (int)cvt_pk_bf16(xv[2], xv[3]);
      pk.z = (int)cvt_pk_bf16(xv[4], xv[5]);
      pk.w = (int)cvt_pk_bf16(xv[6], xv[7]);
      *(int4*)&xb[bufi][swzx(col, 64)] = pk;
      xb[bufi][swzx(col, 72)] = f2bf(xv[8]);
    }
  };

  // per-tile compute phases
  f32x4 acc2[8];
  auto layer1_h1 = [&](int tt) {      // L1 from xb[tt&1] -> hb[tt&1]
    f32x4 acc1[8];
#pragma unroll
    for (int nf = 0; nf < 8; ++nf) acc1[nf] = f32x4{0.f,0.f,0.f,0.f};
    const short* xs = xb[tt & 1];
#pragma unroll
    for (int ks = 0; ks < 3; ++ks) {
      bf16x8 bv[8];
#pragma unroll
      for (int nf = 0; nf < 8; ++nf)
        bv[nf] = *(const bf16x8*)&xs[swzx(16*nf + l15, 32*ks + 8*l4)];
#pragma unroll
      for (int nf = 0; nf < 8; ++nf)
        acc1[nf] = __builtin_amdgcn_mfma_f32_16x16x32_bf16(
            w1f[ks], bv[nf], acc1[nf], 0, 0, 0);
    }
    short* hs = hb[tt & 1];
#pragma unroll
    for (int nf = 0; nf < 8; ++nf) {
      const int col = 16*nf + l15;
      const int row0 = 16*wv + 4*l4;
      uint2 pk;
      pk.x = cvt_pk_bf16(fmaxf(acc1[nf][0], 0.f), fmaxf(acc1[nf][1], 0.f));
      pk.y = cvt_pk_bf16(fmaxf(acc1[nf][2], 0.f), fmaxf(acc1[nf][3], 0.f));
      *(uint2*)&hs[swzh(col, row0)] = pk;
    }
  };
  auto layer2 = [&](int tt) {         // SWAPPED: D[s-sub][outrow=l15]
#pragma unroll
    for (int nf = 0; nf < 8; ++nf) acc2[nf] = f32x4{0.f,0.f,0.f,0.f};
    const short* hs = hb[tt & 1];
#pragma unroll
    for (int ks = 0; ks < 4; ++ks) {
      bf16x8 bv[8];
#pragma unroll
      for (int nf = 0; nf < 8; ++nf)
        bv[nf] = *(const bf16x8*)&hs[swzh(16*nf + l15, 32*ks + 8*l4)];
#pragma unroll
      for (int nf = 0; nf < 8; ++nf)
        acc2[nf] = __builtin_amdgcn_mfma_f32_16x16x32_bf16(
            bv[nf], w2f[ks], acc2[nf], 0, 0, 0);   // A=h1-frag, B=w2-frag
    }
  };

  // ----- prologue -----
  stage(0);
  fill(0, 0);
  stage(1);
  __syncthreads();                 // xb[0] visible
  layer1_h1(0);                    // hb[0]
  fill(1, 1);
  stage(2);
  __syncthreads();                 // hb[0], xb[1] visible

  // ----- main loop: one barrier per tile -----
  for (int it = 0; it < TPB; ++it) {
    const int tile = tile0 + it;
    const int bb = tile >> 8;
    const int pb = (tile & 255) * 4;

    layer2(it);                    // reads hb[it&1]

    // ----- pool: acc2[nf][r] = h2[s=16*(nf&1)+4*l4+r][row=16*wv+l15] -----
    float m[8];
#pragma unroll
    for (int nf = 0; nf < 8; ++nf)
      m[nf] = fmaxf(fmaxf(acc2[nf][0], acc2[nf][1]),
                    fmaxf(acc2[nf][2], acc2[nf][3]));      // reg (s mod 4)
    float vp[4];
#pragma unroll
    for (int p = 0; p < 4; ++p) {
      float v = fmaxf(m[2*p], m[2*p+1]);                   // s halves
      v = fmaxf(v, __shfl_xor(v, 16));                     // l4 pairs
      v = fmaxf(v, __shfl_xor(v, 32));                     // all l4
      vp[p] = fmaxf(v + bias2s, 0.f);
    }
    // one unmasked 64-lane store: row = 16*wv + l15, point = l4
    float vsel = (l4 == 0) ? vp[0] : (l4 == 1) ? vp[1] : (l4 == 2) ? vp[2] : vp[3];
    out[(size_t)(bb*131 + 3 + 16*wv + l15)*NP + pb + l4] = vsel;

    if (it + 1 < TPB) layer1_h1(it + 1);   // xb[(it+1)&1] -> hb[(it+1)&1]
    if (it + 2 < TPB) fill(it + 2, it & 1);
    if (it + 3 < TPB) stage(it + 3);
    if (it + 1 < TPB) __syncthreads();
  }
}

extern "C" void kernel_launch(void* const* d_in, const int* in_sizes, int n_in,
                              void* d_out, int out_size, void* d_ws, size_t ws_size,
                              hipStream_t stream) {
  const float* inp    = (const float*)d_in[0];
  const float* normal = (const float*)d_in[1];
  const float* w1     = (const float*)d_in[2];
  const float* b1     = (const float*)d_in[3];
  const float* w2     = (const float*)d_in[4];
  const float* b2     = (const float*)d_in[5];
  float* out = (float*)d_out;

  // 4096 four-point tiles / TPB=16 -> 256 blocks = 1/CU (122.9 KB LDS)
  mlp_kernel<<<dim3(NB*NP/4/TPB), dim3(512), 0, stream>>>(
      inp, w1, b1, w2, b2, normal, out);
}

// Round 15
// 56.616 us; speedup vs baseline: 4.7122x; 1.0781x over previous
//
#include <hip/hip_runtime.h>
#include <hip/hip_bf16.h>

#define NB 16
#define NP 1024
#define NS 32
#define NC 76
#define XSTR 104   // xb k-stride (shorts): 96 used + 8 pad
#define HSTR 136   // hb k-stride (shorts): 128 used + 8 pad
#define TPB 16     // 4-point tiles per block; 4096 tiles -> 256 blocks = 1/CU

typedef __attribute__((ext_vector_type(8))) short bf16x8;
typedef __attribute__((ext_vector_type(4))) float f32x4;

__device__ inline short f2bf(float f) {
  unsigned u = __builtin_bit_cast(unsigned, f);
  u = u + 0x7fffu + ((u >> 16) & 1u);   // RNE
  return (short)(u >> 16);
}
__device__ inline unsigned cvt_pk_bf16(float lo, float hi) {
  unsigned r;
  asm("v_cvt_pk_bf16_f32 %0, %1, %2" : "=v"(r) : "v"(lo), "v"(hi));
  return r;
}
// Swizzle: fold col bits 4..6 (uniform per 16-col fragment window -> read
// bank-pattern untouched) into addr bits 3..5 (16B-granular). Bijective.
__device__ inline int swzx(int col, int k) {
  return (col * XSTR + k) ^ (((col >> 4) & 7) << 3);
}
__device__ inline int swzh(int col, int k) {
  return (col * HSTR + k) ^ (((col >> 4) & 7) << 3);
}
// sum within 16-lane groups via DPP (frames azi reduce)
__device__ inline float dpp_add16(float v) {
  int x;
  x = __builtin_amdgcn_update_dpp(0, __builtin_bit_cast(int, v), 0xB1, 0xf, 0xf, true);
  v += __builtin_bit_cast(float, x);
  x = __builtin_amdgcn_update_dpp(0, __builtin_bit_cast(int, v), 0x4E, 0xf, 0xf, true);
  v += __builtin_bit_cast(float, x);
  x = __builtin_amdgcn_update_dpp(0, __builtin_bit_cast(int, v), 0x141, 0xf, 0xf, true);
  v += __builtin_bit_cast(float, x);
  x = __builtin_amdgcn_update_dpp(0, __builtin_bit_cast(int, v), 0x140, 0xf, 0xf, true);
  v += __builtin_bit_cast(float, x);
  return v;
}

// ---------------- single fused kernel: frames + MLP + pool ----------------
// R14 skeleton (1 block/CU, TPB=16, dbuf, 1 barrier/tile, fused frames,
// swapped L2 + cheap pool) + R15: 4x2 WAVE GRID — wave (wr=wv>>1, wc=wv&1)
// owns rows 32*wr..+31 (mf=0,1) x cols 64*wc..+63 (nf=0..3, points 2wc,2wc+1).
// Each B-fragment is read by 4 waves instead of 8 -> LDS read volume per tile
// halves (448 -> 224 b128), attacking the measured ~85%-busy LDS pipe (R14).
// Swapped L2: acc2[mf][nf] = mfma(A=h1-frag, B=w2f[mf]) -> lane holds
// h2[outrow=32wr+16mf+l15][s = 16*(nf&1)+4*l4+reg, point = 2wc+(nf>>1)].
// Pool: 3 fmax (reg) + 1 fmax (nf pair) + shfl_xor(16,32) (l4) per (mf,pp);
// store: one unmasked 64-lane op, mf=l4>>1, point=l4&1.
// xb [col][k]: 0..63 feats(ch12..75); 64..66 R*rel; 67..69 R*o_n; 70..72
// dir_dif; 73 = 1.0 (bias-1 row, static); 74..95 = 0 (static).
__global__ __launch_bounds__(512, 2)
void mlp_kernel(const float* __restrict__ inp, const float* __restrict__ w1g,
                const float* __restrict__ b1g, const float* __restrict__ w2g,
                const float* __restrict__ b2g, const float* __restrict__ normal,
                float* __restrict__ out) {
  __shared__ short xb[2][128 * XSTR];   // 2 x 26,624 B
  __shared__ short hb[2][128 * HSTR];   // 2 x 34,816 B
  const int tid = threadIdx.x;
  const int lane = tid & 63;
  const int wv = tid >> 6;
  const int wr = wv >> 1;           // row-stripe 0..3 -> rows 32*wr..
  const int wc = wv & 1;            // col-half 0..1 -> cols 64*wc..
  const int l15 = lane & 15;
  const int l4 = lane >> 4;         // 0..3

  const int tile0 = blockIdx.x * TPB;

  // fill-phase thread map (feats)
  const int s4  = tid & 7;          // s quad
  const int flp = (tid >> 3) & 3;   // point within tile
  const int chq = tid >> 5;         // channel quad 0..15 -> k = 4*chq
  const int colb = flp*32 + 4*s4;

  // ----- weight fragments (rows 32*wr+16*mf+l15); b1 folded at kk=73 -----
  bf16x8 w1f[2][3];
#pragma unroll
  for (int mf = 0; mf < 2; ++mf)
#pragma unroll
    for (int ks = 0; ks < 3; ++ks) {
      bf16x8 a;
#pragma unroll
      for (int j = 0; j < 8; ++j) {
        int row = 32*wr + 16*mf + l15;
        int kk = 32*ks + 8*l4 + j;
        float v = 0.f;
        if (kk < 73) {
          int c = (kk < 64) ? (kk + 3) : ((kk < 67) ? (kk - 64) : kk);
          v = w1g[row*73 + c];
        } else if (kk == 73) {
          v = b1g[row];
        }
        a[j] = f2bf(v);
      }
      w1f[mf][ks] = a;
    }
  bf16x8 w2f[2][4];
#pragma unroll
  for (int mf = 0; mf < 2; ++mf)
#pragma unroll
    for (int ks = 0; ks < 4; ++ks) {
      const float* wp = w2g + (size_t)(32*wr + 16*mf + l15)*128 + 32*ks + 8*l4;
      float4 a0 = *(const float4*)wp;
      float4 a1 = *(const float4*)(wp + 4);
      bf16x8 a;
      a[0] = f2bf(a0.x); a[1] = f2bf(a0.y); a[2] = f2bf(a0.z); a[3] = f2bf(a0.w);
      a[4] = f2bf(a1.x); a[5] = f2bf(a1.y); a[6] = f2bf(a1.z); a[7] = f2bf(a1.w);
      w2f[mf][ks] = a;
    }
  float bias2[2];
#pragma unroll
  for (int mf = 0; mf < 2; ++mf) bias2[mf] = b2g[32*wr + 16*mf + l15];

  // static pad region of BOTH xb buffers: k=73 -> 1.0, (73,96) -> 0
  for (int i = tid; i < 2*128*23; i += 512) {
    int bufi = i / (128*23);
    int r = i - bufi*(128*23);
    int col = r / 23;
    int k = 73 + (r - col*23);
    xb[bufi][swzx(col, k)] = (k == 73) ? (short)0x3F80 : (short)0;
  }

  // ----- staging registers -----
  float4 sf0, sf1, sf2, sf3;    // feats: 4 channels x 4 s
  float sro[9];                 // rel/o_n/o_dir for (p, s) (tid<128)
  auto stage = [&](int it2) {
    const int tile = tile0 + it2;
    const int bb = tile >> 8;
    const int pb = (tile & 255) * 4;
    const float* base = inp + ((size_t)((bb*NC + 12 + 4*chq)*NP) + pb + flp)*NS + 4*s4;
    sf0 = *(const float4*)(base + 0*(size_t)NP*NS);
    sf1 = *(const float4*)(base + 1*(size_t)NP*NS);
    sf2 = *(const float4*)(base + 2*(size_t)NP*NS);
    sf3 = *(const float4*)(base + 3*(size_t)NP*NS);
    if (tid < 128) {
      const int lp = tid >> 5, s = tid & 31;
      const int p = pb + lp;
#pragma unroll
      for (int i = 0; i < 3; ++i) {
        sro[i]   = inp[(size_t)((bb*NC + 6 + i)*NP + p)*NS + s];   // rel
        sro[3+i] = inp[(size_t)((bb*NC + 3 + i)*NP + p)*NS + s];   // o_n
        sro[6+i] = inp[(size_t)((bb*NC + 9 + i)*NP + p)*NS + s];   // o_dir
      }
    }
  };

  auto fill = [&](int it2, int bufi) {
    const int tile = tile0 + it2;
    const int bb = tile >> 8;
    const int pb = (tile & 255) * 4;
    float nr[3];
    if (tid < 128) {   // issue normal loads early (hide under feat writes)
      const int p = pb + (tid >> 5);
#pragma unroll
      for (int i = 0; i < 3; ++i) nr[i] = normal[(size_t)(bb*NP + p)*3 + i];
    }
    const float* f0 = (const float*)&sf0;
    const float* f1 = (const float*)&sf1;
    const float* f2 = (const float*)&sf2;
    const float* f3 = (const float*)&sf3;
#pragma unroll
    for (int j = 0; j < 4; ++j) {
      uint2 pk;
      pk.x = cvt_pk_bf16(f0[j], f1[j]);
      pk.y = cvt_pk_bf16(f2[j], f3[j]);
      *(uint2*)&xb[bufi][swzx(colb + j, 4*chq)] = pk;
    }
    if (tid < 128) {
      const int col = tid;
      const int s = col & 31;
      const int p = pb + (col >> 5);
      // azi = mean over s=1..31 (16-lane DPP sum + xor16 within the s-group)
      float az[3];
#pragma unroll
      for (int i = 0; i < 3; ++i) {
        float sum = dpp_add16(sro[i]);
        sum += __shfl_xor(sum, 16);
        float v0 = __shfl(sro[i], lane & 32);    // s==0 lane of this group
        az[i] = (sum - v0) * (1.f/31.f);
      }
      float nn = sqrtf(nr[0]*nr[0] + nr[1]*nr[1] + nr[2]*nr[2]) + 1e-8f;
      nr[0] /= nn; nr[1] /= nn; nr[2] /= nn;
      float an = sqrtf(az[0]*az[0] + az[1]*az[1] + az[2]*az[2]) + 1e-8f;
      float au[3] = {az[0]/an, az[1]/an, az[2]/an};
      float d = au[0]*nr[0] + au[1]*nr[1] + au[2]*nr[2];
      float xax[3] = {au[0] - d*nr[0], au[1] - d*nr[1], au[2] - d*nr[2]};
      float xn = sqrtf(xax[0]*xax[0] + xax[1]*xax[1] + xax[2]*xax[2]) + 1e-8f;
      xax[0] /= xn; xax[1] /= xn; xax[2] /= xn;
      float yax[3] = {nr[1]*xax[2] - nr[2]*xax[1],
                      nr[2]*xax[0] - nr[0]*xax[2],
                      nr[0]*xax[1] - nr[1]*xax[0]};
      if (s < 3) {    // azi_u -> out channels 0..2
        float o = (s == 0) ? au[0] : ((s == 1) ? au[1] : au[2]);
        out[(size_t)(bb*131 + s)*NP + p] = o;
      }
      float xv[9];
#pragma unroll
      for (int r = 0; r < 3; ++r) {
        const float* Rr = (r == 0) ? xax : ((r == 1) ? yax : nr);
        xv[r]   = Rr[0]*sro[0] + Rr[1]*sro[1] + Rr[2]*sro[2];
        xv[3+r] = Rr[0]*sro[3] + Rr[1]*sro[4] + Rr[2]*sro[5];
        xv[6+r] = (Rr[0]*au[0] + Rr[1]*au[1] + Rr[2]*au[2])
                - (Rr[0]*sro[6] + Rr[1]*sro[7] + Rr[2]*sro[8]);
      }
      int4 pk;
      pk.x = (int)cvt_pk_bf16(xv[0], xv[1]);
      pk.y = (int)cvt_pk_bf16(xv[2], xv[3]);
      pk.z = (int)cvt_pk_bf16(xv[4], xv[5]);
      pk.w = (int)cvt_pk_bf16(xv[6], xv[7]);
      *(int4*)&xb[bufi][swzx(col, 64)] = pk;
      xb[bufi][swzx(col, 72)] = f2bf(xv[8]);
    }
  };

  // per-tile compute phases
  f32x4 acc2[2][4];
  auto layer1_h1 = [&](int tt) {      // L1 from xb[tt&1] -> hb[tt&1]
    f32x4 acc1[2][4];
#pragma unroll
    for (int mf = 0; mf < 2; ++mf)
#pragma unroll
      for (int nf = 0; nf < 4; ++nf) acc1[mf][nf] = f32x4{0.f,0.f,0.f,0.f};
    const short* xs = xb[tt & 1];
#pragma unroll
    for (int ks = 0; ks < 3; ++ks) {
      bf16x8 bv[4];
#pragma unroll
      for (int nf = 0; nf < 4; ++nf)
        bv[nf] = *(const bf16x8*)&xs[swzx(64*wc + 16*nf + l15, 32*ks + 8*l4)];
#pragma unroll
      for (int mf = 0; mf < 2; ++mf)
#pragma unroll
        for (int nf = 0; nf < 4; ++nf)
          acc1[mf][nf] = __builtin_amdgcn_mfma_f32_16x16x32_bf16(
              w1f[mf][ks], bv[nf], acc1[mf][nf], 0, 0, 0);
    }
    short* hs = hb[tt & 1];
#pragma unroll
    for (int mf = 0; mf < 2; ++mf)
#pragma unroll
      for (int nf = 0; nf < 4; ++nf) {
        const int col = 64*wc + 16*nf + l15;
        const int row0 = 32*wr + 16*mf + 4*l4;
        uint2 pk;
        pk.x = cvt_pk_bf16(fmaxf(acc1[mf][nf][0], 0.f), fmaxf(acc1[mf][nf][1], 0.f));
        pk.y = cvt_pk_bf16(fmaxf(acc1[mf][nf][2], 0.f), fmaxf(acc1[mf][nf][3], 0.f));
        *(uint2*)&hs[swzh(col, row0)] = pk;
      }
  };
  auto layer2 = [&](int tt) {         // SWAPPED: D[tile-col-sub][outrow=l15]
#pragma unroll
    for (int mf = 0; mf < 2; ++mf)
#pragma unroll
      for (int nf = 0; nf < 4; ++nf) acc2[mf][nf] = f32x4{0.f,0.f,0.f,0.f};
    const short* hs = hb[tt & 1];
#pragma unroll
    for (int ks = 0; ks < 4; ++ks) {
      bf16x8 bv[4];
#pragma unroll
      for (int nf = 0; nf < 4; ++nf)
        bv[nf] = *(const bf16x8*)&hs[swzh(64*wc + 16*nf + l15, 32*ks + 8*l4)];
#pragma unroll
      for (int mf = 0; mf < 2; ++mf)
#pragma unroll
        for (int nf = 0; nf < 4; ++nf)
          acc2[mf][nf] = __builtin_amdgcn_mfma_f32_16x16x32_bf16(
              bv[nf], w2f[mf][ks], acc2[mf][nf], 0, 0, 0);  // A=h1, B=w2
    }
  };

  // ----- prologue -----
  stage(0);
  fill(0, 0);
  stage(1);
  __syncthreads();                 // xb[0] visible
  layer1_h1(0);                    // hb[0]
  fill(1, 1);
  stage(2);
  __syncthreads();                 // hb[0], xb[1] visible

  // ----- main loop: one barrier per tile -----
  for (int it = 0; it < TPB; ++it) {
    const int tile = tile0 + it;
    const int bb = tile >> 8;
    const int pb = (tile & 255) * 4;

    layer2(it);                    // reads hb[it&1]

    // ----- pool: acc2[mf][nf][r] = h2[32wr+16mf+l15][s=16*(nf&1)+4*l4+r],
    //             point = 2*wc + (nf>>1) -----
    float vp[2][2];
#pragma unroll
    for (int mf = 0; mf < 2; ++mf) {
      float m[4];
#pragma unroll
      for (int nf = 0; nf < 4; ++nf)
        m[nf] = fmaxf(fmaxf(acc2[mf][nf][0], acc2[mf][nf][1]),
                      fmaxf(acc2[mf][nf][2], acc2[mf][nf][3]));  // reg (s%4)
#pragma unroll
      for (int pp = 0; pp < 2; ++pp) {
        float v = fmaxf(m[2*pp], m[2*pp+1]);                     // s halves
        v = fmaxf(v, __shfl_xor(v, 16));                         // l4 pairs
        v = fmaxf(v, __shfl_xor(v, 32));                         // all l4
        vp[mf][pp] = fmaxf(v + bias2[mf], 0.f);
      }
    }
    // one unmasked 64-lane store: row = 32wr+16*(l4>>1)+l15, pt = 2wc+(l4&1)
    float vsel = (l4 == 0) ? vp[0][0] : (l4 == 1) ? vp[0][1]
               : (l4 == 2) ? vp[1][0] : vp[1][1];
    out[(size_t)(bb*131 + 3 + 32*wr + 16*(l4 >> 1) + l15)*NP + pb + 2*wc + (l4 & 1)] = vsel;

    if (it + 1 < TPB) layer1_h1(it + 1);   // xb[(it+1)&1] -> hb[(it+1)&1]
    if (it + 2 < TPB) fill(it + 2, it & 1);
    if (it + 3 < TPB) stage(it + 3);
    if (it + 1 < TPB) __syncthreads();
  }
}

extern "C" void kernel_launch(void* const* d_in, const int* in_sizes, int n_in,
                              void* d_out, int out_size, void* d_ws, size_t ws_size,
                              hipStream_t stream) {
  const float* inp    = (const float*)d_in[0];
  const float* normal = (const float*)d_in[1];
  const float* w1     = (const float*)d_in[2];
  const float* b1     = (const float*)d_in[3];
  const float* w2     = (const float*)d_in[4];
  const float* b2     = (const float*)d_in[5];
  float* out = (float*)d_out;

  // 4096 four-point tiles / TPB=16 -> 256 blocks = 1/CU (122.9 KB LDS)
  mlp_kernel<<<dim3(NB*NP/4/TPB), dim3(512), 0, stream>>>(
      inp, w1, b1, w2, b2, normal, out);
}